// Round 11
// baseline (169.993 us; speedup 1.0000x reference)
//
#include <hip/hip_runtime.h>
#include <hip/hip_bf16.h>
#include <math.h>

#define NB 4
#define NC 128
#define NN 4096

typedef short s16x8 __attribute__((ext_vector_type(8)));
typedef float f32x4 __attribute__((ext_vector_type(4)));
typedef float f32x16 __attribute__((ext_vector_type(16)));
typedef unsigned int u32;

extern "C" __device__ float __ocml_native_exp2_f32(float);

__device__ __forceinline__ unsigned short f2b(float f) {
    __hip_bfloat16 h = __float2bfloat16(f);
    return *reinterpret_cast<unsigned short*>(&h);
}
__device__ __forceinline__ u32 f2b2(float lo, float hi) {
    __hip_bfloat162 h2 = __float22bfloat162_rn(make_float2(lo, hi));
    return *reinterpret_cast<u32*>(&h2);
}

// ---------------------------------------------------------------------------
// prep: convert W/bias -> bf16 once (log2e/sqrt(C) folded into wq,bq).
// Wb layout [o][c], o: 0-15 q, 16-31 k, 32-159 v. Grid 80 x 256.
// ---------------------------------------------------------------------------
__global__ __launch_bounds__(256) void prep_kernel(
    const float* __restrict__ wq, const float* __restrict__ bq,
    const float* __restrict__ wk, const float* __restrict__ bk,
    const float* __restrict__ wv, const float* __restrict__ bv,
    unsigned short* __restrict__ Wb, float* __restrict__ Bf)
{
    const float s = 1.4426950408889634f / sqrtf(128.0f);
    const int idx = blockIdx.x * 256 + threadIdx.x;   // 0..20479
    const int o = idx >> 7, c = idx & 127;
    float v;
    if (o < 16)      v = wq[o * 128 + c] * s;
    else if (o < 32) v = wk[(o - 16) * 128 + c];
    else             v = wv[(o - 32) * 128 + c];
    Wb[o * 128 + c] = f2b(v);
    if (blockIdx.x == 0 && threadIdx.x < 160) {
        const int oo = threadIdx.x;
        Bf[oo] = (oo < 16) ? bq[oo] * s : (oo < 32) ? bk[oo - 16] : bv[oo - 32];
    }
}

// ---------------------------------------------------------------------------
// proj: QKV projection, pure-register MFMA GEMM (no LDS, no barriers).
// Grid 512 (b x 32px), 256 thr: wave = (pxt, o-half).
// Qb/Kb bf16 [b][n][16]; V2 bf16 [b][m/16][c][16] (PV-fragment-ready tiles).
// ---------------------------------------------------------------------------
__global__ __launch_bounds__(256, 2) void proj_kernel(
    const float* __restrict__ x, const unsigned short* __restrict__ Wb,
    const float* __restrict__ Bf,
    unsigned short* __restrict__ Qb, unsigned short* __restrict__ Kb,
    unsigned short* __restrict__ V2)
{
    const int t = threadIdx.x;
    const int lane = t & 63, w = t >> 6;
    const int l = lane & 15, h = lane >> 4;
    const int pxt = w & 1, oh = w >> 1;
    const int b = blockIdx.x >> 7;
    const int n0 = (blockIdx.x & 127) * 32;
    const int n = n0 + pxt * 16 + l;

    // B-fragments from x columns (fp32 -> bf16), reused across all o-tiles
    s16x8 bx[4];
#pragma unroll
    for (int ks = 0; ks < 4; ++ks) {
        float xv[8];
#pragma unroll
        for (int j = 0; j < 8; ++j)
            xv[j] = x[((size_t)(b * 128 + ks * 32 + h * 8 + j)) * 4096 + n];
        u32* pw = (u32*)&bx[ks];
        pw[0] = f2b2(xv[0], xv[1]);
        pw[1] = f2b2(xv[2], xv[3]);
        pw[2] = f2b2(xv[4], xv[5]);
        pw[3] = f2b2(xv[6], xv[7]);
    }

#pragma unroll
    for (int i = 0; i < 5; ++i) {
        const int ot = oh * 5 + i;
        const int o0 = ot * 16;
        f32x4 acc = (f32x4){0.f, 0.f, 0.f, 0.f};
#pragma unroll
        for (int ks = 0; ks < 4; ++ks) {
            const s16x8 wf = *(const s16x8*)&Wb[(o0 + l) * 128 + ks * 32 + h * 8];
            acc = __builtin_amdgcn_mfma_f32_16x16x32_bf16(wf, bx[ks], acc, 0, 0, 0);
        }
        const float r0 = acc[0] + Bf[o0 + h * 4 + 0];
        const float r1 = acc[1] + Bf[o0 + h * 4 + 1];
        const float r2 = acc[2] + Bf[o0 + h * 4 + 2];
        const float r3 = acc[3] + Bf[o0 + h * 4 + 3];
        if (ot == 0) {
            uint2 pk_; pk_.x = f2b2(r0, r1); pk_.y = f2b2(r2, r3);
            *(uint2*)&Qb[((size_t)b * 4096 + n) * 16 + h * 4] = pk_;
        } else if (ot == 1) {
            uint2 pk_; pk_.x = f2b2(r0, r1); pk_.y = f2b2(r2, r3);
            *(uint2*)&Kb[((size_t)b * 4096 + n) * 16 + h * 4] = pk_;
        } else {
            const int c0 = (ot - 2) * 16 + h * 4;
            const size_t base = ((size_t)(b * 256 + (n >> 4))) * 128 * 16 + (n & 15);
            V2[base + (size_t)(c0 + 0) * 16] = f2b(r0);
            V2[base + (size_t)(c0 + 1) * 16] = f2b(r1);
            V2[base + (size_t)(c0 + 2) * 16] = f2b(r2);
            V2[base + (size_t)(c0 + 3) * 16] = f2b(r3);
        }
    }
}

// ---------------------------------------------------------------------------
// attn: flash attention, 32x32x16 MFMA, all operands from global->registers.
// Grid 512 (one 32-row q-tile each), 256 thr: wave = (ch c-half, kvs KV-half).
// Zero barriers in main loop; 2 barriers in the KV-split merge epilogue.
// ---------------------------------------------------------------------------
__global__ __launch_bounds__(256, 2) void attn_kernel(
    const unsigned short* __restrict__ Qb, const unsigned short* __restrict__ Kb,
    const unsigned short* __restrict__ V2, const float* __restrict__ x,
    const float* __restrict__ gammap, float* __restrict__ out)
{
    __shared__ float mlsM[2][32], mlsL[2][32];
    __shared__ float buf[2][64][36];    // +pad to 36 -> conflict-spread

    const int t = threadIdx.x;
    const int lane = t & 63, w = t >> 6;
    const int ch = w & 1, kvs = w >> 1;
    const int n31 = lane & 31, h5 = lane >> 5;

    // XCD-pair-per-batch block swizzle (bid%8 = XCD)
    const int bid = blockIdx.x;
    const int xcd = bid & 7;
    const int b = xcd >> 1;
    const int qt = ((bid >> 3) << 1) | (xcd & 1);   // 0..127
    const int n = qt * 32 + n31;

    // Q B-fragment: col n = lane&31, k(d) = h5*8+j
    const s16x8 qf = *(const s16x8*)&Qb[((size_t)b * 4096 + n) * 16 + h5 * 8];

    f32x16 z16;
#pragma unroll
    for (int r = 0; r < 16; ++r) z16[r] = 0.0f;

    float mrun = -1e30f, lrun = 0.0f;
    f32x16 acc0 = z16, acc1 = z16;      // ct=0,1: c = ch*64 + ct*32 + row

    const unsigned short* Kbb = Kb + (size_t)b * 4096 * 16;
    const unsigned short* Vbb = V2 + (size_t)b * 256 * 128 * 16;

    for (int step = 0; step < 32; ++step) {
        const int m0 = kvs * 2048 + step * 64;

        // ---- V fragments for this step (independent: issue first) ----
        s16x8 vf[4][2];
#pragma unroll
        for (int kb = 0; kb < 4; ++kb) {
            const size_t vt = (size_t)((m0 >> 4) + kb) * 128 * 16;
            vf[kb][0] = *(const s16x8*)&Vbb[vt + (size_t)(ch * 64 + n31) * 16 + h5 * 8];
            vf[kb][1] = *(const s16x8*)&Vbb[vt + (size_t)(ch * 64 + 32 + n31) * 16 + h5 * 8];
        }
        // ---- K fragments + S = K.Q^T (D[m][n], col n lane-local) ----
        const s16x8 kf0 = *(const s16x8*)&Kbb[(size_t)(m0 + n31) * 16 + h5 * 8];
        const s16x8 kf1 = *(const s16x8*)&Kbb[(size_t)(m0 + 32 + n31) * 16 + h5 * 8];
        f32x16 s0 = __builtin_amdgcn_mfma_f32_32x32x16_bf16(kf0, qf, z16, 0, 0, 0);
        f32x16 s1 = __builtin_amdgcn_mfma_f32_32x32x16_bf16(kf1, qf, z16, 0, 0, 0);

        // ---- online softmax over m: in-lane tree + one shfl_xor(32) ----
        float mx[8];
#pragma unroll
        for (int r = 0; r < 8; ++r)
            mx[r] = fmaxf(fmaxf(s0[r], s0[r + 8]), fmaxf(s1[r], s1[r + 8]));
#pragma unroll
        for (int d = 4; d > 0; d >>= 1)
#pragma unroll
            for (int r = 0; r < d; ++r) mx[r] = fmaxf(mx[r], mx[r + d]);
        const float pmax = fmaxf(mx[0], __shfl_xor(mx[0], 32));
        const float mnew = fmaxf(mrun, pmax);
        const float rr = __ocml_native_exp2_f32(mrun - mnew);
        float lsum = 0.f;
#pragma unroll
        for (int r = 0; r < 16; ++r) {
            s0[r] = __ocml_native_exp2_f32(s0[r] - mnew); lsum += s0[r];
            s1[r] = __ocml_native_exp2_f32(s1[r] - mnew); lsum += s1[r];
        }
        lsum += __shfl_xor(lsum, 32);
        lrun = lrun * rr + lsum;
        mrun = mnew;
#pragma unroll
        for (int r = 0; r < 16; ++r) { acc0[r] *= rr; acc1[r] *= rr; }

        // ---- P -> bf16 pairs + cross-half exchange (no LDS) ----
        u32 q2[16], x2[16];
#pragma unroll
        for (int i = 0; i < 8; ++i) {
            q2[i]     = f2b2(s0[2 * i], s0[2 * i + 1]);
            q2[8 + i] = f2b2(s1[2 * i], s1[2 * i + 1]);
        }
#pragma unroll
        for (int i = 0; i < 16; ++i)
            x2[i] = (u32)__shfl_xor((int)q2[i], 32);

        // ---- PV: D[c][n] += V[c][m] . P[m][n] ----
#pragma unroll
        for (int kb = 0; kb < 4; ++kb) {
            const int base = (kb >> 1) * 8 + (kb & 1) * 4;
            s16x8 pf;
            u32* pw = (u32*)&pf;
            pw[0] = h5 ? x2[base + 2] : q2[base + 0];
            pw[1] = h5 ? x2[base + 3] : q2[base + 1];
            pw[2] = h5 ? q2[base + 2] : x2[base + 0];
            pw[3] = h5 ? q2[base + 3] : x2[base + 1];
            acc0 = __builtin_amdgcn_mfma_f32_32x32x16_bf16(vf[kb][0], pf, acc0, 0, 0, 0);
            acc1 = __builtin_amdgcn_mfma_f32_32x32x16_bf16(vf[kb][1], pf, acc1, 0, 0, 0);
        }
    }

    // ---- KV-split merge (2 partials) ----
    if (ch == 0 && h5 == 0) { mlsM[kvs][n31] = mrun; mlsL[kvs][n31] = lrun; }
    __syncthreads();
    const float ma = mlsM[0][n31], mb = mlsM[1][n31];
    const float mg = fmaxf(ma, mb);
    const float lg = __ocml_native_exp2_f32(ma - mg) * mlsL[0][n31]
                   + __ocml_native_exp2_f32(mb - mg) * mlsL[1][n31];
    const float sc = __ocml_native_exp2_f32(mrun - mg);
#pragma unroll
    for (int r = 0; r < 16; ++r) { acc0[r] *= sc; acc1[r] *= sc; }

    if (kvs == 1) {
#pragma unroll
        for (int r = 0; r < 16; ++r) {
            buf[ch][lane][r]      = acc0[r];
            buf[ch][lane][16 + r] = acc1[r];
        }
    }
    __syncthreads();
    if (kvs == 0) {
        const float g = gammap[0];
        const float inv = 1.0f / lg;
#pragma unroll
        for (int r = 0; r < 16; ++r) {
            acc0[r] += buf[ch][lane][r];
            acc1[r] += buf[ch][lane][16 + r];
        }
#pragma unroll
        for (int ct = 0; ct < 2; ++ct)
#pragma unroll
            for (int r = 0; r < 16; ++r) {
                const int c = ch * 64 + ct * 32 + (r & 3) + 8 * (r >> 2) + 4 * h5;
                const size_t idx = ((size_t)b * 128 + c) * 4096 + n;
                const float v = (ct == 0) ? acc0[r] : acc1[r];
                out[idx] = g * (v * inv) + x[idx];
            }
    }
}

// ---------------------------------------------------------------------------
extern "C" void kernel_launch(void* const* d_in, const int* in_sizes, int n_in,
                              void* d_out, int out_size, void* d_ws, size_t ws_size,
                              hipStream_t stream)
{
    const float* x  = (const float*)d_in[0];
    const float* wq = (const float*)d_in[1];
    const float* bq = (const float*)d_in[2];
    const float* wk = (const float*)d_in[3];
    const float* bk = (const float*)d_in[4];
    const float* wv = (const float*)d_in[5];
    const float* bv = (const float*)d_in[6];
    const float* gm = (const float*)d_in[7];
    float* out = (float*)d_out;

    unsigned short* Wb = (unsigned short*)d_ws;                       // 40 KB
    float*          Bf = (float*)((char*)d_ws + 40960);               // 640 B
    unsigned short* Qb = (unsigned short*)((char*)d_ws + 41600);      // 512 KB
    unsigned short* Kb = Qb + (size_t)NB * NN * 16;                   // 512 KB
    unsigned short* V2 = Kb + (size_t)NB * NN * 16;                   // 4 MB

    hipLaunchKernelGGL(prep_kernel, dim3(80), dim3(256), 0, stream,
                       wq, bq, wk, bk, wv, bv, Wb, Bf);
    hipLaunchKernelGGL(proj_kernel, dim3(512), dim3(256), 0, stream,
                       x, Wb, Bf, Qb, Kb, V2);
    hipLaunchKernelGGL(attn_kernel, dim3(512), dim3(256), 0, stream,
                       Qb, Kb, V2, x, gm, out);
}